// Round 5
// baseline (4977.704 us; speedup 1.0000x reference)
//
#include <hip/hip_runtime.h>
#include <math.h>

#define S_LEN 256
#define NCELL 8
#define HID 16
#define MEM 20
#define NB 2
#define NTHR 1024
#define KT 64
#define RPAD 68

typedef _Float16 h2 __attribute__((ext_vector_type(2)));

#if defined(__has_builtin)
#if __has_builtin(__builtin_amdgcn_fdot2)
#define HAVE_FDOT2 1
#endif
#endif

__device__ __forceinline__ float sigm(float v) { return 1.0f / (1.0f + __expf(-v)); }
__device__ __forceinline__ float tanh_f(float v) { return 1.0f - 2.0f / (__expf(2.0f * v) + 1.0f); }
__device__ __forceinline__ float dot4(float4 a, float4 b) {
    return fmaf(a.x, b.x, fmaf(a.y, b.y, fmaf(a.z, b.z, a.w * b.w)));
}
__device__ __forceinline__ float dot2acc(h2 a, h2 w, float c) {
#ifdef HAVE_FDOT2
    return __builtin_amdgcn_fdot2(a, w, c, false);
#else
    return fmaf((float)a.x, (float)w.x, fmaf((float)a.y, (float)w.y, c));
#endif
}

// R3/R4 lesson: the allocator targets 128 VGPRs for this kernel regardless of
// waves_per_eu hints, spilling a 160-reg W1 slice (WRITE_SIZE 23.7 MB).
// Fix: 1024 threads, 64-way K-split -> per-thread W1 slice = 80 VGPRs,
// peak live ~115 < 128 -> cannot spill. Also doubles occupancy (4 waves/EU).
__global__ __attribute__((amdgpu_flat_work_group_size(NTHR, NTHR)))
void mmoe_kernel(const float* __restrict__ x, const float* __restrict__ pred0,
                 const float* __restrict__ gate0,
                 const float* __restrict__ W_ih, const float* __restrict__ W_hh,
                 const float* __restrict__ b_ih, const float* __restrict__ b_hh,
                 const float* __restrict__ W_o, const float* __restrict__ b_o,
                 const float* __restrict__ W1, const float* __restrict__ b1,
                 const float* __restrict__ W2, const float* __restrict__ b2,
                 const float* __restrict__ Wg, const float* __restrict__ bg,
                 const float* __restrict__ Wa_ih, const float* __restrict__ Wa_hh,
                 const float* __restrict__ ba_ih, const float* __restrict__ ba_hh,
                 float* __restrict__ out)
{
    __shared__ __align__(16) _Float16 ringH[NB][MEM][128];   // memory rows (h part), f16
    __shared__ float errS[NB][MEM];                          // error column, f32
    __shared__ __align__(16) float Whh_l[512 * 20];          // stride 20 (bank pad)
    __shared__ float Wih_l[512], bias_l[512];
    __shared__ __align__(16) float WaI[2][64 * 20], WaH[2][64 * 20];
    __shared__ float ba_l[2][64];
    __shared__ __align__(16) float W2_l[16 * 68];
    __shared__ float b2_l[16];
    __shared__ __align__(16) float Wg_l[8][16], Wo_l[8][16];
    __shared__ float bg_l[8], bo_l[8];
    __shared__ float Werr_l[MEM * 64];                       // W1 col-128 slices (f32)
    __shared__ float b1_l[64];
    __shared__ float xS[NB][S_LEN];
    __shared__ __align__(16) float ehS[NB][HID], ecS[NB][HID];
    __shared__ __align__(16) float nhS[NB][NCELL][HID], ncS[NB][NCELL][HID];
    __shared__ float oS[NB][NCELL], predS[NB], gateS[NB][NCELL];
    __shared__ __align__(16) float ahS[2][NB][HID], acS[2][NB][HID];
    __shared__ __align__(16) float e1S[NB][64], aiS[NB][HID];
    __shared__ __align__(16) float glog[NB][8];
    __shared__ __align__(16) float red[NB][KT][RPAD];        // phase-B split-K partials

    const int tid = threadIdx.x;
    const int b0 = blockIdx.x * NB;
    const int jg = tid & 15, kg = tid >> 4;                  // 16 j-groups x 64 k-groups
    const int j0 = jg * 4, c0 = kg * 2;                      // 4 j-cols, 2 f16 k-cols per m-row

    // ---- one-time staging: global -> LDS ----
    for (int i = tid; i < 512 * 16; i += NTHR) { int g = i >> 4, q = i & 15; Whh_l[g * 20 + q] = W_hh[i]; }
    for (int i = tid; i < 512; i += NTHR) { Wih_l[i] = W_ih[i]; bias_l[i] = b_ih[i] + b_hh[i]; }
    for (int i = tid; i < 2048; i += NTHR) {
        int l = i >> 10, r = i & 1023, g = r >> 4, q = r & 15;
        WaI[l][g * 20 + q] = Wa_ih[i]; WaH[l][g * 20 + q] = Wa_hh[i];
    }
    for (int i = tid; i < 128; i += NTHR) { int l = i >> 6, g = i & 63; ba_l[l][g] = ba_ih[i] + ba_hh[i]; }
    for (int i = tid; i < 1024; i += NTHR) { int r = i >> 6, q = i & 63; W2_l[r * 68 + q] = W2[i]; }
    for (int i = tid; i < 1280; i += NTHR) { int m = i >> 6, j = i & 63; Werr_l[i] = W1[j * 2580 + m * 129 + 128]; }
    if (tid < 64) b1_l[tid] = b1[tid];
    if (tid < 16) b2_l[tid] = b2[tid];
    if (tid < 128) { int c = tid >> 4, h = tid & 15; Wg_l[c][h] = Wg[tid]; Wo_l[c][h] = W_o[tid]; }
    if (tid < 8) { bg_l[tid] = bg[tid]; bo_l[tid] = b_o[tid]; }
    for (int i = tid; i < NB * S_LEN; i += NTHR) { int b = i >> 8, s = i & 255; xS[b][s] = x[(b0 + b) * S_LEN + s]; }
    // state init
    for (int i = tid; i < NB * MEM * 128; i += NTHR) ((_Float16*)ringH)[i] = (_Float16)0.0f;
    if (tid < NB * MEM) { int b = tid / MEM, m = tid % MEM; errS[b][m] = 0.5f; }
    if (tid < NB * HID) {
        int b = tid >> 4, h = tid & 15;
        ehS[b][h] = 0.f; ecS[b][h] = 0.f;
        ahS[0][b][h] = 0.f; ahS[1][b][h] = 0.f;
        acS[0][b][h] = 0.f; acS[1][b][h] = 0.f;
    }
    if (tid < NB) predS[tid] = pred0[b0 + tid];
    if (tid < NB * NCELL) { int b = tid >> 3, c = tid & 7; gateS[b][c] = gate0[(b0 + b) * NCELL + c]; }

    // ---- register-resident W1 slice (f16): 20 m x 4 j x 1 h2 = 80 VGPRs ----
    h2 w1r[MEM][4];
    #pragma unroll
    for (int m = 0; m < MEM; ++m)
        #pragma unroll
        for (int jj = 0; jj < 4; ++jj) {
            const float* wp = &W1[(size_t)(j0 + jj) * 2580 + m * 129 + c0];
            h2 w;
            w[0] = (_Float16)wp[0]; w[1] = (_Float16)wp[1];
            w1r[m][jj] = w;
        }
    __syncthreads();

    int head = 0;
    #pragma unroll 1
    for (int t = 0; t < S_LEN; ++t) {
        head = (head == 0) ? (MEM - 1) : (head - 1);

        // ---- Phase A (tid<256): 8 expert LSTM cells ----
        if (tid < 256) {
            int b = tid >> 7, c = (tid >> 4) & 7, h = tid & 15;
            float xv = xS[b][t];
            const float4* ep = (const float4*)&ehS[b][0];
            float4 e0 = ep[0], e1v = ep[1], e2 = ep[2], e3 = ep[3];
            float zg[4];
            #pragma unroll
            for (int gi = 0; gi < 4; ++gi) {
                int g = c * 64 + gi * 16 + h;
                const float* wr = &Whh_l[g * 20];
                float z = bias_l[g] + xv * Wih_l[g];
                z += dot4(e0, *(const float4*)&wr[0]) + dot4(e1v, *(const float4*)&wr[4])
                   + dot4(e2, *(const float4*)&wr[8]) + dot4(e3, *(const float4*)&wr[12]);
                zg[gi] = z;
            }
            float cc = ecS[b][h];
            float c2 = sigm(zg[1]) * cc + sigm(zg[0]) * tanh_f(zg[2]);
            float hv = sigm(zg[3]) * tanh_f(c2);
            nhS[b][c][h] = hv; ncS[b][c][h] = c2;
            ringH[b][head][c * 16 + h] = (_Float16)hv;
            if (tid < NB) errS[tid][head] = xS[tid][t] - predS[tid];
        }
        __syncthreads();

        // ---- Phase B (all 1024): e1 partials via register-resident f16 W1 ----
        {
            float acc[NB][4] = {};
            #pragma unroll
            for (int m = 0; m < MEM; ++m) {
                int s = head + m; if (s >= MEM) s -= MEM;
                h2 aA = *(const h2*)&ringH[0][s][c0];
                h2 aB = *(const h2*)&ringH[1][s][c0];
                #pragma unroll
                for (int jj = 0; jj < 4; ++jj) {
                    acc[0][jj] = dot2acc(aA, w1r[m][jj], acc[0][jj]);
                    acc[1][jj] = dot2acc(aB, w1r[m][jj], acc[1][jj]);
                }
            }
            *(float4*)&red[0][kg][j0] = make_float4(acc[0][0], acc[0][1], acc[0][2], acc[0][3]);
            *(float4*)&red[1][kg][j0] = make_float4(acc[1][0], acc[1][1], acc[1][2], acc[1][3]);
        }
        __syncthreads();

        // ---- Phase R (tid<128): reduce split-K + f32 error column + bias + relu ----
        if (tid < 128) {
            int bb = tid >> 6, j = tid & 63;
            float s0 = 0.f, s1 = 0.f, s2 = 0.f, s3 = 0.f;
            #pragma unroll
            for (int g = 0; g < 16; ++g) {
                s0 += red[bb][4 * g + 0][j];
                s1 += red[bb][4 * g + 1][j];
                s2 += red[bb][4 * g + 2][j];
                s3 += red[bb][4 * g + 3][j];
            }
            float v = b1_l[j] + ((s0 + s1) + (s2 + s3));
            float u0 = 0.f, u1 = 0.f;
            #pragma unroll
            for (int m = 0; m < MEM; m += 2) {
                int sa = head + m; if (sa >= MEM) sa -= MEM;
                int sb = head + m + 1; if (sb >= MEM) sb -= MEM;
                u0 = fmaf(Werr_l[m * 64 + j], errS[bb][sa], u0);
                u1 = fmaf(Werr_l[(m + 1) * 64 + j], errS[bb][sb], u1);
            }
            e1S[bb][j] = fmaxf(v + u0 + u1, 0.f);
        }
        __syncthreads();

        // ---- Tail (wave 0 only; intra-wave LDS ordering, no barriers inside) ----
        if (tid < 64) {
            const int j = tid;
            if (j < 32) {
                int bb = j >> 4, i = j & 15;
                const float4* epq = (const float4*)&e1S[bb][0];
                float s = b2_l[i];
                #pragma unroll
                for (int q = 0; q < 16; ++q) s += dot4(*(const float4*)&W2_l[i * 68 + q * 4], epq[q]);
                aiS[bb][i] = fmaxf(s, 0.f);
            } else if (j < 48) {
                int q = j - 32, bb = q >> 3, c = q & 7;
                const float4* np = (const float4*)&nhS[bb][c][0];
                const float4* wp = (const float4*)&Wo_l[c][0];
                float s = bo_l[c];
                #pragma unroll
                for (int q4 = 0; q4 < 4; ++q4) s += dot4(np[q4], wp[q4]);
                oS[bb][c] = s;
            }
            #pragma unroll
            for (int l = 0; l < 2; ++l) {
                if (j < 32) {
                    int bb = j >> 4, h = j & 15;
                    const float4* ip = (l == 0) ? (const float4*)&aiS[bb][0]
                                                : (const float4*)&ahS[0][bb][0];
                    const float4* hp = (const float4*)&ahS[l][bb][0];
                    float4 i0 = ip[0], i1 = ip[1], i2 = ip[2], i3 = ip[3];
                    float4 h0 = hp[0], h1 = hp[1], h2v = hp[2], h3 = hp[3];
                    float zg[4];
                    #pragma unroll
                    for (int gi = 0; gi < 4; ++gi) {
                        int g = gi * 16 + h;
                        const float* wi = &WaI[l][g * 20];
                        const float* wh = &WaH[l][g * 20];
                        float z = ba_l[l][g];
                        z += dot4(i0, *(const float4*)&wi[0]) + dot4(i1, *(const float4*)&wi[4])
                           + dot4(i2, *(const float4*)&wi[8]) + dot4(i3, *(const float4*)&wi[12]);
                        z += dot4(h0, *(const float4*)&wh[0]) + dot4(h1, *(const float4*)&wh[4])
                           + dot4(h2v, *(const float4*)&wh[8]) + dot4(h3, *(const float4*)&wh[12]);
                        zg[gi] = z;
                    }
                    float c2 = sigm(zg[1]) * acS[l][bb][h] + sigm(zg[0]) * tanh_f(zg[2]);
                    acS[l][bb][h] = c2;
                    ahS[l][bb][h] = sigm(zg[3]) * tanh_f(c2);
                }
            }
            if (j < 16) {
                int bb = j >> 3, c = j & 7;
                const float4* hp = (const float4*)&ahS[1][bb][0];
                const float4* wg = (const float4*)&Wg_l[c][0];
                float s = bg_l[c];
                #pragma unroll
                for (int q = 0; q < 4; ++q) s += dot4(wg[q], hp[q]);
                glog[bb][c] = s;
                float4 ga = *(const float4*)&glog[bb][0];
                float4 gb = *(const float4*)&glog[bb][4];
                float mx = fmaxf(fmaxf(fmaxf(ga.x, ga.y), fmaxf(ga.z, ga.w)),
                                 fmaxf(fmaxf(gb.x, gb.y), fmaxf(gb.z, gb.w)));
                float sum = __expf(ga.x - mx) + __expf(ga.y - mx) + __expf(ga.z - mx) + __expf(ga.w - mx)
                          + __expf(gb.x - mx) + __expf(gb.y - mx) + __expf(gb.z - mx) + __expf(gb.w - mx);
                float p = __expf(s - mx) / sum;
                float th = 0.f;
                #pragma unroll
                for (int m = 0; m < 10; ++m) {
                    int sl = head + m; if (sl >= MEM) sl -= MEM;
                    th += fabsf(errS[bb][sl]);
                }
                th *= 0.25f;
                th = fminf(fmaxf(th, 0.f), 1.f);
                gateS[bb][c] = p * th + gateS[bb][c] * (1.f - th);
            }
            if (j < 32) {
                int bb = j >> 4, h = j & 15;
                float se = 0.f, sc = 0.f;
                #pragma unroll
                for (int c = 0; c < 8; ++c) {
                    float g = gateS[bb][c];
                    se = fmaf(g, nhS[bb][c][h], se);
                    sc = fmaf(g, ncS[bb][c][h], sc);
                }
                ehS[bb][h] = se; ecS[bb][h] = sc;
            } else if (j < 32 + NB) {
                int bb = j - 32;
                float s = 0.f;
                #pragma unroll
                for (int c = 0; c < 8; ++c) s = fmaf(gateS[bb][c], oS[bb][c], s);
                predS[bb] = s;
                out[(b0 + bb) * S_LEN + t] = s;
            }
        }
        __syncthreads();
    }
}

extern "C" void kernel_launch(void* const* d_in, const int* in_sizes, int n_in,
                              void* d_out, int out_size, void* d_ws, size_t ws_size,
                              hipStream_t stream) {
    const float* xp    = (const float*)d_in[0];
    const float* pred0 = (const float*)d_in[1];
    const float* gate0 = (const float*)d_in[2];
    const float* W_ih  = (const float*)d_in[3];
    const float* W_hh  = (const float*)d_in[4];
    const float* b_ih  = (const float*)d_in[5];
    const float* b_hh  = (const float*)d_in[6];
    const float* W_o   = (const float*)d_in[7];
    const float* b_o   = (const float*)d_in[8];
    const float* W1    = (const float*)d_in[9];
    const float* b1    = (const float*)d_in[10];
    const float* W2    = (const float*)d_in[11];
    const float* b2    = (const float*)d_in[12];
    const float* Wg    = (const float*)d_in[13];
    const float* bg    = (const float*)d_in[14];
    const float* Wa_ih = (const float*)d_in[15];
    const float* Wa_hh = (const float*)d_in[16];
    const float* ba_ih = (const float*)d_in[17];
    const float* ba_hh = (const float*)d_in[18];

    mmoe_kernel<<<512 / NB, NTHR, 0, stream>>>(
        xp, pred0, gate0, W_ih, W_hh, b_ih, b_hh, W_o, b_o,
        W1, b1, W2, b2, Wg, bg, Wa_ih, Wa_hh, ba_ih, ba_hh,
        (float*)d_out);
}

// Round 6
// 1818.737 us; speedup vs baseline: 2.7369x; 2.7369x over previous
//
#include <hip/hip_runtime.h>
#include <math.h>

#define S_LEN 256
#define NCELL 8
#define HID 16
#define MEM 20
#define NB 2
#define NTHR 512
#define KT 32
#define RPAD 68

typedef _Float16 h2 __attribute__((ext_vector_type(2)));
typedef _Float16 h4 __attribute__((ext_vector_type(4)));

#if defined(__has_builtin)
#if __has_builtin(__builtin_amdgcn_fdot2)
#define HAVE_FDOT2 1
#endif
#endif

__device__ __forceinline__ float sigm(float v) { return 1.0f / (1.0f + __expf(-v)); }
__device__ __forceinline__ float tanh_f(float v) { return 1.0f - 2.0f / (__expf(2.0f * v) + 1.0f); }
__device__ __forceinline__ float dot4(float4 a, float4 b) {
    return fmaf(a.x, b.x, fmaf(a.y, b.y, fmaf(a.z, b.z, a.w * b.w)));
}
__device__ __forceinline__ float dot2acc(h2 a, h2 w, float c) {
#ifdef HAVE_FDOT2
    return __builtin_amdgcn_fdot2(a, w, c, false);
#else
    return fmaf((float)a.x, (float)w.x, fmaf((float)a.y, (float)w.y, c));
#endif
}

// R2-R5 lesson: ANY per-thread array for the W1 slice stays an alloca in
// scratch (AMDGPUPromoteAlloca cap), VGPR_Count then tracks the occupancy
// heuristic (320->216,160->128,80->64) and scratch traffic dominates.
// Fix: 160 *named* h2 SSA variables (no alloca exists) + waves_per_eu(2,2)
// for a 256-VGPR budget. Demand ~200 < 256 -> register-resident at last.

#define DECL_M(M) h2 w##M##_00, w##M##_01, w##M##_10, w##M##_11, \
                     w##M##_20, w##M##_21, w##M##_30, w##M##_31;

#define INIT_M(M) { \
    const float* wpA = &W1[(size_t)(j0 + 0) * 2580 + (M) * 129 + c0]; \
    const float* wpB = &W1[(size_t)(j0 + 1) * 2580 + (M) * 129 + c0]; \
    const float* wpC = &W1[(size_t)(j0 + 2) * 2580 + (M) * 129 + c0]; \
    const float* wpD = &W1[(size_t)(j0 + 3) * 2580 + (M) * 129 + c0]; \
    w##M##_00[0] = (_Float16)wpA[0]; w##M##_00[1] = (_Float16)wpA[1]; \
    w##M##_01[0] = (_Float16)wpA[2]; w##M##_01[1] = (_Float16)wpA[3]; \
    w##M##_10[0] = (_Float16)wpB[0]; w##M##_10[1] = (_Float16)wpB[1]; \
    w##M##_11[0] = (_Float16)wpB[2]; w##M##_11[1] = (_Float16)wpB[3]; \
    w##M##_20[0] = (_Float16)wpC[0]; w##M##_20[1] = (_Float16)wpC[1]; \
    w##M##_21[0] = (_Float16)wpC[2]; w##M##_21[1] = (_Float16)wpC[3]; \
    w##M##_30[0] = (_Float16)wpD[0]; w##M##_30[1] = (_Float16)wpD[1]; \
    w##M##_31[0] = (_Float16)wpD[2]; w##M##_31[1] = (_Float16)wpD[3]; }

#define DOT_M(M) { \
    int s = head + (M); if (s >= MEM) s -= MEM; \
    h4 vA = *(const h4*)&ringH[0][s][c0]; \
    h4 vB = *(const h4*)&ringH[1][s][c0]; \
    h2 aA0; aA0[0] = vA[0]; aA0[1] = vA[1]; \
    h2 aA1; aA1[0] = vA[2]; aA1[1] = vA[3]; \
    h2 aB0; aB0[0] = vB[0]; aB0[1] = vB[1]; \
    h2 aB1; aB1[0] = vB[2]; aB1[1] = vB[3]; \
    a00 = dot2acc(aA0, w##M##_00, a00); a00 = dot2acc(aA1, w##M##_01, a00); \
    a01 = dot2acc(aA0, w##M##_10, a01); a01 = dot2acc(aA1, w##M##_11, a01); \
    a02 = dot2acc(aA0, w##M##_20, a02); a02 = dot2acc(aA1, w##M##_21, a02); \
    a03 = dot2acc(aA0, w##M##_30, a03); a03 = dot2acc(aA1, w##M##_31, a03); \
    a10 = dot2acc(aB0, w##M##_00, a10); a10 = dot2acc(aB1, w##M##_01, a10); \
    a11 = dot2acc(aB0, w##M##_10, a11); a11 = dot2acc(aB1, w##M##_11, a11); \
    a12 = dot2acc(aB0, w##M##_20, a12); a12 = dot2acc(aB1, w##M##_21, a12); \
    a13 = dot2acc(aB0, w##M##_30, a13); a13 = dot2acc(aB1, w##M##_31, a13); }

#define REP20(X) X(0) X(1) X(2) X(3) X(4) X(5) X(6) X(7) X(8) X(9) \
                 X(10) X(11) X(12) X(13) X(14) X(15) X(16) X(17) X(18) X(19)

__global__ __attribute__((amdgpu_flat_work_group_size(NTHR, NTHR),
                          amdgpu_waves_per_eu(2, 2)))
void mmoe_kernel(const float* __restrict__ x, const float* __restrict__ pred0,
                 const float* __restrict__ gate0,
                 const float* __restrict__ W_ih, const float* __restrict__ W_hh,
                 const float* __restrict__ b_ih, const float* __restrict__ b_hh,
                 const float* __restrict__ W_o, const float* __restrict__ b_o,
                 const float* __restrict__ W1, const float* __restrict__ b1,
                 const float* __restrict__ W2, const float* __restrict__ b2,
                 const float* __restrict__ Wg, const float* __restrict__ bg,
                 const float* __restrict__ Wa_ih, const float* __restrict__ Wa_hh,
                 const float* __restrict__ ba_ih, const float* __restrict__ ba_hh,
                 float* __restrict__ out)
{
    __shared__ __align__(16) _Float16 ringH[NB][MEM][128];   // memory rows (h part), f16
    __shared__ float errS[NB][MEM];                          // error column, f32
    __shared__ __align__(16) float Whh_l[512 * 20];          // stride 20 (bank pad)
    __shared__ float Wih_l[512], bias_l[512];
    __shared__ __align__(16) float WaI[2][64 * 20], WaH[2][64 * 20];
    __shared__ float ba_l[2][64];
    __shared__ __align__(16) float W2_l[16 * 68];
    __shared__ float b2_l[16];
    __shared__ __align__(16) float Wg_l[8][16], Wo_l[8][16];
    __shared__ float bg_l[8], bo_l[8];
    __shared__ float Werr_l[MEM * 64];                       // W1 col-128 slices (f32)
    __shared__ float b1_l[64];
    __shared__ float xS[NB][S_LEN];
    __shared__ __align__(16) float ehS[NB][HID], ecS[NB][HID];
    __shared__ __align__(16) float nhS[NB][NCELL][HID], ncS[NB][NCELL][HID];
    __shared__ float oS[NB][NCELL], predS[NB], gateS[NB][NCELL];
    __shared__ __align__(16) float ahS[2][NB][HID], acS[2][NB][HID];
    __shared__ __align__(16) float e1S[NB][64], aiS[NB][HID];
    __shared__ __align__(16) float glog[NB][8];
    __shared__ __align__(16) float red[NB][KT][RPAD];        // phase-B split-K partials

    const int tid = threadIdx.x;
    const int b0 = blockIdx.x * NB;
    const int jg = tid & 15, kg = tid >> 4;                  // 16 j-groups x 32 k-groups
    const int j0 = jg * 4, c0 = kg * 4;                      // 4 j-cols, 4 f16 k-cols per m-row

    // ---- one-time staging: global -> LDS ----
    for (int i = tid; i < 512 * 16; i += NTHR) { int g = i >> 4, q = i & 15; Whh_l[g * 20 + q] = W_hh[i]; }
    for (int i = tid; i < 512; i += NTHR) { Wih_l[i] = W_ih[i]; bias_l[i] = b_ih[i] + b_hh[i]; }
    for (int i = tid; i < 2048; i += NTHR) {
        int l = i >> 10, r = i & 1023, g = r >> 4, q = r & 15;
        WaI[l][g * 20 + q] = Wa_ih[i]; WaH[l][g * 20 + q] = Wa_hh[i];
    }
    for (int i = tid; i < 128; i += NTHR) { int l = i >> 6, g = i & 63; ba_l[l][g] = ba_ih[i] + ba_hh[i]; }
    for (int i = tid; i < 1024; i += NTHR) { int r = i >> 6, q = i & 63; W2_l[r * 68 + q] = W2[i]; }
    for (int i = tid; i < 1280; i += NTHR) { int m = i >> 6, j = i & 63; Werr_l[i] = W1[j * 2580 + m * 129 + 128]; }
    if (tid < 64) b1_l[tid] = b1[tid];
    if (tid < 16) b2_l[tid] = b2[tid];
    if (tid < 128) { int c = tid >> 4, h = tid & 15; Wg_l[c][h] = Wg[tid]; Wo_l[c][h] = W_o[tid]; }
    if (tid < 8) { bg_l[tid] = bg[tid]; bo_l[tid] = b_o[tid]; }
    for (int i = tid; i < NB * S_LEN; i += NTHR) { int b = i >> 8, s = i & 255; xS[b][s] = x[(b0 + b) * S_LEN + s]; }
    // state init
    for (int i = tid; i < NB * MEM * 128; i += NTHR) ((_Float16*)ringH)[i] = (_Float16)0.0f;
    if (tid < NB * MEM) { int b = tid / MEM, m = tid % MEM; errS[b][m] = 0.5f; }
    if (tid < NB * HID) {
        int b = tid >> 4, h = tid & 15;
        ehS[b][h] = 0.f; ecS[b][h] = 0.f;
        ahS[0][b][h] = 0.f; ahS[1][b][h] = 0.f;
        acS[0][b][h] = 0.f; acS[1][b][h] = 0.f;
    }
    if (tid < NB) predS[tid] = pred0[b0 + tid];
    if (tid < NB * NCELL) { int b = tid >> 3, c = tid & 7; gateS[b][c] = gate0[(b0 + b) * NCELL + c]; }

    // ---- register-resident W1 slice: 160 NAMED h2 SSA values (no alloca) ----
    REP20(DECL_M)
    REP20(INIT_M)
    __syncthreads();

    int head = 0;
    #pragma unroll 1
    for (int t = 0; t < S_LEN; ++t) {
        head = (head == 0) ? (MEM - 1) : (head - 1);

        // ---- Phase A (tid<256): 8 expert LSTM cells ----
        if (tid < 256) {
            int b = tid >> 7, c = (tid >> 4) & 7, h = tid & 15;
            float xv = xS[b][t];
            const float4* ep = (const float4*)&ehS[b][0];
            float4 e0 = ep[0], e1v = ep[1], e2 = ep[2], e3 = ep[3];
            float zg[4];
            #pragma unroll
            for (int gi = 0; gi < 4; ++gi) {
                int g = c * 64 + gi * 16 + h;
                const float* wr = &Whh_l[g * 20];
                float z = bias_l[g] + xv * Wih_l[g];
                z += dot4(e0, *(const float4*)&wr[0]) + dot4(e1v, *(const float4*)&wr[4])
                   + dot4(e2, *(const float4*)&wr[8]) + dot4(e3, *(const float4*)&wr[12]);
                zg[gi] = z;
            }
            float cc = ecS[b][h];
            float c2 = sigm(zg[1]) * cc + sigm(zg[0]) * tanh_f(zg[2]);
            float hv = sigm(zg[3]) * tanh_f(c2);
            nhS[b][c][h] = hv; ncS[b][c][h] = c2;
            ringH[b][head][c * 16 + h] = (_Float16)hv;
            if (tid < NB) errS[tid][head] = xS[tid][t] - predS[tid];
        }
        __syncthreads();

        // ---- Phase B (all 512): e1 partials, register-resident f16 W1 ----
        {
            float a00 = 0.f, a01 = 0.f, a02 = 0.f, a03 = 0.f;
            float a10 = 0.f, a11 = 0.f, a12 = 0.f, a13 = 0.f;
            REP20(DOT_M)
            *(float4*)&red[0][kg][j0] = make_float4(a00, a01, a02, a03);
            *(float4*)&red[1][kg][j0] = make_float4(a10, a11, a12, a13);
        }
        __syncthreads();

        // ---- Phase R (tid<128): reduce split-K + f32 error column + bias + relu ----
        if (tid < 128) {
            int bb = tid >> 6, j = tid & 63;
            float s0 = 0.f, s1 = 0.f, s2 = 0.f, s3 = 0.f;
            #pragma unroll
            for (int g = 0; g < 8; ++g) {
                s0 += red[bb][4 * g + 0][j];
                s1 += red[bb][4 * g + 1][j];
                s2 += red[bb][4 * g + 2][j];
                s3 += red[bb][4 * g + 3][j];
            }
            float v = b1_l[j] + ((s0 + s1) + (s2 + s3));
            float u0 = 0.f, u1 = 0.f;
            #pragma unroll
            for (int m = 0; m < MEM; m += 2) {
                int sa = head + m; if (sa >= MEM) sa -= MEM;
                int sb = head + m + 1; if (sb >= MEM) sb -= MEM;
                u0 = fmaf(Werr_l[m * 64 + j], errS[bb][sa], u0);
                u1 = fmaf(Werr_l[(m + 1) * 64 + j], errS[bb][sb], u1);
            }
            e1S[bb][j] = fmaxf(v + u0 + u1, 0.f);
        }
        __syncthreads();

        // ---- Tail (wave 0 only; intra-wave LDS ordering, no barriers inside) ----
        if (tid < 64) {
            const int j = tid;
            if (j < 32) {
                int bb = j >> 4, i = j & 15;
                const float4* epq = (const float4*)&e1S[bb][0];
                float s = b2_l[i];
                #pragma unroll
                for (int q = 0; q < 16; ++q) s += dot4(*(const float4*)&W2_l[i * 68 + q * 4], epq[q]);
                aiS[bb][i] = fmaxf(s, 0.f);
            } else if (j < 48) {
                int q = j - 32, bb = q >> 3, c = q & 7;
                const float4* np = (const float4*)&nhS[bb][c][0];
                const float4* wp = (const float4*)&Wo_l[c][0];
                float s = bo_l[c];
                #pragma unroll
                for (int q4 = 0; q4 < 4; ++q4) s += dot4(np[q4], wp[q4]);
                oS[bb][c] = s;
            }
            #pragma unroll
            for (int l = 0; l < 2; ++l) {
                if (j < 32) {
                    int bb = j >> 4, h = j & 15;
                    const float4* ip = (l == 0) ? (const float4*)&aiS[bb][0]
                                                : (const float4*)&ahS[0][bb][0];
                    const float4* hp = (const float4*)&ahS[l][bb][0];
                    float4 i0 = ip[0], i1 = ip[1], i2 = ip[2], i3 = ip[3];
                    float4 h0 = hp[0], h1 = hp[1], h2v = hp[2], h3 = hp[3];
                    float zg[4];
                    #pragma unroll
                    for (int gi = 0; gi < 4; ++gi) {
                        int g = gi * 16 + h;
                        const float* wi = &WaI[l][g * 20];
                        const float* wh = &WaH[l][g * 20];
                        float z = ba_l[l][g];
                        z += dot4(i0, *(const float4*)&wi[0]) + dot4(i1, *(const float4*)&wi[4])
                           + dot4(i2, *(const float4*)&wi[8]) + dot4(i3, *(const float4*)&wi[12]);
                        z += dot4(h0, *(const float4*)&wh[0]) + dot4(h1, *(const float4*)&wh[4])
                           + dot4(h2v, *(const float4*)&wh[8]) + dot4(h3, *(const float4*)&wh[12]);
                        zg[gi] = z;
                    }
                    float c2 = sigm(zg[1]) * acS[l][bb][h] + sigm(zg[0]) * tanh_f(zg[2]);
                    acS[l][bb][h] = c2;
                    ahS[l][bb][h] = sigm(zg[3]) * tanh_f(c2);
                }
            }
            if (j < 16) {
                int bb = j >> 3, c = j & 7;
                const float4* hp = (const float4*)&ahS[1][bb][0];
                const float4* wg = (const float4*)&Wg_l[c][0];
                float s = bg_l[c];
                #pragma unroll
                for (int q = 0; q < 4; ++q) s += dot4(wg[q], hp[q]);
                glog[bb][c] = s;
                float4 ga = *(const float4*)&glog[bb][0];
                float4 gb = *(const float4*)&glog[bb][4];
                float mx = fmaxf(fmaxf(fmaxf(ga.x, ga.y), fmaxf(ga.z, ga.w)),
                                 fmaxf(fmaxf(gb.x, gb.y), fmaxf(gb.z, gb.w)));
                float sum = __expf(ga.x - mx) + __expf(ga.y - mx) + __expf(ga.z - mx) + __expf(ga.w - mx)
                          + __expf(gb.x - mx) + __expf(gb.y - mx) + __expf(gb.z - mx) + __expf(gb.w - mx);
                float p = __expf(s - mx) / sum;
                float th = 0.f;
                #pragma unroll
                for (int m = 0; m < 10; ++m) {
                    int sl = head + m; if (sl >= MEM) sl -= MEM;
                    th += fabsf(errS[bb][sl]);
                }
                th *= 0.25f;
                th = fminf(fmaxf(th, 0.f), 1.f);
                gateS[bb][c] = p * th + gateS[bb][c] * (1.f - th);
            }
            if (j < 32) {
                int bb = j >> 4, h = j & 15;
                float se = 0.f, sc = 0.f;
                #pragma unroll
                for (int c = 0; c < 8; ++c) {
                    float g = gateS[bb][c];
                    se = fmaf(g, nhS[bb][c][h], se);
                    sc = fmaf(g, ncS[bb][c][h], sc);
                }
                ehS[bb][h] = se; ecS[bb][h] = sc;
            } else if (j < 32 + NB) {
                int bb = j - 32;
                float s = 0.f;
                #pragma unroll
                for (int c = 0; c < 8; ++c) s = fmaf(gateS[bb][c], oS[bb][c], s);
                predS[bb] = s;
                out[(b0 + bb) * S_LEN + t] = s;
            }
        }
        __syncthreads();
    }
}

extern "C" void kernel_launch(void* const* d_in, const int* in_sizes, int n_in,
                              void* d_out, int out_size, void* d_ws, size_t ws_size,
                              hipStream_t stream) {
    const float* xp    = (const float*)d_in[0];
    const float* pred0 = (const float*)d_in[1];
    const float* gate0 = (const float*)d_in[2];
    const float* W_ih  = (const float*)d_in[3];
    const float* W_hh  = (const float*)d_in[4];
    const float* b_ih  = (const float*)d_in[5];
    const float* b_hh  = (const float*)d_in[6];
    const float* W_o   = (const float*)d_in[7];
    const float* b_o   = (const float*)d_in[8];
    const float* W1    = (const float*)d_in[9];
    const float* b1    = (const float*)d_in[10];
    const float* W2    = (const float*)d_in[11];
    const float* b2    = (const float*)d_in[12];
    const float* Wg    = (const float*)d_in[13];
    const float* bg    = (const float*)d_in[14];
    const float* Wa_ih = (const float*)d_in[15];
    const float* Wa_hh = (const float*)d_in[16];
    const float* ba_ih = (const float*)d_in[17];
    const float* ba_hh = (const float*)d_in[18];

    mmoe_kernel<<<512 / NB, NTHR, 0, stream>>>(
        xp, pred0, gate0, W_ih, W_hh, b_ih, b_hh, W_o, b_o,
        W1, b1, W2, b2, Wg, bg, Wa_ih, Wa_hh, ba_ih, ba_hh,
        (float*)d_out);
}